// Round 11
// baseline (54.938 us; speedup 1.0000x reference)
//
#include <hip/hip_runtime.h>
#include <hip/hip_bf16.h>

// Problem constants (fixed by reference):
#define SS 512
#define HH 768
#define LL 32
#define DD 1536   // 2*H
#define MM 2048   // B*L rows
#define KA 768    // main-GEMM K (mean half only; CLS half collapses to C2)
#define NSTEP 12  // K-steps of 64

typedef float f32x4 __attribute__((ext_vector_type(4)));
typedef short bf16x8 __attribute__((ext_vector_type(8)));

__device__ __forceinline__ unsigned short f2bf(float x) {
    union { float f; unsigned u; } v; v.f = x;
    unsigned r = v.u + 0x7fff + ((v.u >> 16) & 1);   // round-to-nearest-even
    return (unsigned short)(r >> 16);
}

__device__ __forceinline__ float bf2f(unsigned short x) {
    union { unsigned u; float f; } t; t.u = ((unsigned)x) << 16; return t.f;
}

__device__ __forceinline__ void gload16(const unsigned short* g, unsigned short* l) {
    // async global->LDS, 16B/lane; LDS dest = wave-uniform base + lane*16
    __builtin_amdgcn_global_load_lds(
        (const __attribute__((address_space(1))) void*)g,
        (__attribute__((address_space(3))) void*)l, 16, 0, 0);
}

// ---------------------------------------------------------------------------
// Fused prep, 192 threads (one float4/thread):
//   [0,2048)      : mean rows -> Abf[row][768] bf16
//   [2048,5120)   : W_pool f32->bf16 (full 1536x1536, row-major)
//   [5120,5184)   : cls rows  -> Cls[b][768] bf16   (b = blk-5120)
//   [5184,5195)   : init logits to b_out
// ---------------------------------------------------------------------------
__global__ __launch_bounds__(192)
void prep(const float* __restrict__ seq, const int* __restrict__ pos,
          const float* __restrict__ Wp, const float* __restrict__ bo,
          unsigned short* __restrict__ Abf, unsigned short* __restrict__ Wbf,
          unsigned short* __restrict__ Cls, float* __restrict__ out) {
    const int blk = blockIdx.x;
    const int tid = threadIdx.x;            // 0..191
    if (blk < MM) {
        int b = blk >> 5;
        int l = blk & 31;
        const int* pb = pos + b * (LL + 1);
        int start = pb[l] + 1;
        int end   = pb[l + 1] + 1;
        if (l == LL - 1) end += 1;          // last clause also takes the SEP
        float inv = 1.0f / (float)(end - start);
        const float* base = seq + (size_t)b * SS * HH;
        float4 a = make_float4(0.f, 0.f, 0.f, 0.f);
        for (int t = start; t < end; ++t) {
            float4 v = reinterpret_cast<const float4*>(base + (size_t)t * HH)[tid];
            a.x += v.x; a.y += v.y; a.z += v.z; a.w += v.w;
        }
        ushort4 m;
        m.x = f2bf(a.x * inv); m.y = f2bf(a.y * inv);
        m.z = f2bf(a.z * inv); m.w = f2bf(a.w * inv);
        reinterpret_cast<ushort4*>(Abf + (size_t)blk * KA)[tid] = m;
    } else if (blk < MM + 3072) {
        int i = ((blk - MM) * 192 + tid) * 4;        // DD*DD = 3072*192*4
        float4 v = *(const float4*)(Wp + i);
        ushort4 o;
        o.x = f2bf(v.x); o.y = f2bf(v.y); o.z = f2bf(v.z); o.w = f2bf(v.w);
        *(ushort4*)(Wbf + i) = o;
    } else if (blk < MM + 3072 + 64) {
        int b = blk - MM - 3072;
        float4 c = reinterpret_cast<const float4*>(seq + (size_t)b * SS * HH)[tid];
        ushort4 cc;
        cc.x = f2bf(c.x); cc.y = f2bf(c.y); cc.z = f2bf(c.z); cc.w = f2bf(c.w);
        reinterpret_cast<ushort4*>(Cls + (size_t)b * KA)[tid] = cc;
    } else {
        int i = (blk - MM - 3072 - 64) * 192 + tid;
        if (i < MM) out[i] = bo[0];
    }
}

// ---------------------------------------------------------------------------
// Main GEMM over the MEAN half only (K=768, 12 steps) — exact R7 structure:
// 64x64 tile, 4 waves (2x2 of 32x32), 3 LDS bufs, stage-ahead-2, counted
// vmcnt(4), one barrier/step, verified XOR swizzle (conflict-free), XCD
// chunking (8bm x 12bn per XCD). NEW: per-block VALU prologue computes the
// CLS-half contribution C2[2][64] = cls[2bm+b] . W[col, 768:1536) (bf16 in,
// f32 acc) into LDS; epilogue adds it before tanh. This collapses the CLS
// half of the GEMM 32x (all 32 clauses of a batch share cls).
// Fused epilogue: tanh(accM + C2 + b_pool)*W_out, shfl reduce, atomicAdd.
// ---------------------------------------------------------------------------
__global__ __launch_bounds__(256, 3)
void gemm_mfma(const unsigned short* __restrict__ A,   // [MM][768] bf16 means
               const unsigned short* __restrict__ Bm,  // [DD][DD] bf16 W_pool
               const unsigned short* __restrict__ Cl,  // [64][768] bf16 cls
               const float* __restrict__ bp,           // [DD]
               const float* __restrict__ Wo,           // [DD]
               float* __restrict__ out) {              // [MM]
    __shared__ unsigned short As[3 * 4096];  // 3 bufs x 64x64 bf16 = 24 KB
    __shared__ unsigned short Bs[3 * 4096];  // 24 KB
    __shared__ float c2p[256];               // 1 KB  (C2 partial sums)
    __shared__ float c2s[2][64];             // 0.5 KB (C2 block slice)
    const int tid  = threadIdx.x;
    const int wid  = tid >> 6;
    const int lane = tid & 63;
    const int fr   = lane & 15;
    const int fq   = lane >> 4;
    const int wr   = wid >> 1, wc = wid & 1;

    // XCD-aware chunking: xcd = blk&7 (HW round-robin); chunk 8 bm x 12 bn
    const int blk = blockIdx.x;             // 0..767
    const int c = blk & 7;
    const int i = blk >> 3;                 // 0..95
    const int bm = ((c >> 1) << 3) + (i & 7);     // 0..31
    const int bn = (c & 1) * 12 + (i >> 3);       // 0..23
    const int brow = bm * 64;
    const int bcol = bn * 64;

    // ---- C2 prologue: c2s[b][n] = cls[2bm+b] . W[bcol+n, 768:1536) ----
    {
        const int v = tid & 127;            // value index: b(1b) x n(6b)
        const int cb = v >> 6;              // 0..1
        const int cn = v & 63;              // 0..63
        const int h  = tid >> 7;            // K-half 0/1 (384 each)
        const unsigned short* crow = Cl + (size_t)(2 * bm + cb) * KA + h * 384;
        const unsigned short* wrow = Bm + (size_t)(bcol + cn) * DD + 768 + h * 384;
        float s = 0.f;
        #pragma unroll 4
        for (int kc = 0; kc < 48; ++kc) {
            bf16x8 av = *(const bf16x8*)(crow + kc * 8);
            bf16x8 bv = *(const bf16x8*)(wrow + kc * 8);
            #pragma unroll
            for (int e = 0; e < 8; ++e)
                s = fmaf(bf2f((unsigned short)av[e]),
                         bf2f((unsigned short)bv[e]), s);
        }
        c2p[tid] = s;
    }
    __syncthreads();
    if (tid < 128) c2s[tid >> 6][tid & 63] = c2p[tid] + c2p[tid + 128];
    // (no extra barrier needed: K-loop barriers precede epilogue reads)

    // staging: thread t -> row t>>3 (and +32), 16B chunk (t&7)^(row&7)
    // (source pre-swizzle; LDS dest stays linear per rule #21)
    const int srow = tid >> 3;              // 0..31 ; +32 for second half
    const int sc   = (tid & 7) ^ (srow & 7);      // (srow+32)&7 == srow&7
    const unsigned short* gA = A  + (size_t)(brow + srow) * KA + sc * 8;
    const unsigned short* gB = Bm + (size_t)(bcol + srow) * DD + sc * 8;
    unsigned short* asW = As + wid * 512;   // wave-uniform LDS dest base
    unsigned short* bsW = Bs + wid * 512;

#define STAGE(buf, kt) do {                                          \
        gload16(gA + (kt) * 64,           asW + (buf) * 4096);       \
        gload16(gA + (kt) * 64 + 32 * KA, asW + (buf) * 4096 + 2048);\
        gload16(gB + (kt) * 64,           bsW + (buf) * 4096);       \
        gload16(gB + (kt) * 64 + 32 * DD, bsW + (buf) * 4096 + 2048);\
    } while (0)

    // swizzled fragment-read offsets: slot = desired_chunk ^ (row&7)
    const int s0 = fq ^ (fr & 7);
    const int s1 = s0 ^ 4;
    const int rA = wr * 32 + fr;            // m adds 16
    const int rB = wc * 32 + fr;            // n adds 16
    const int oA00 = rA * 64 + s0 * 8, oA01 = rA * 64 + s1 * 8;
    const int oA10 = oA00 + 16 * 64,   oA11 = oA01 + 16 * 64;
    const int oB00 = rB * 64 + s0 * 8, oB01 = rB * 64 + s1 * 8;
    const int oB10 = oB00 + 16 * 64,   oB11 = oB01 + 16 * 64;

    f32x4 acc[2][2] = {};

    __syncthreads();                        // c2 VMEM drained; c2s visible
    STAGE(0, 0); STAGE(1, 1);               // depth-2 prologue (8 loads/wave)

#define BODY(t, buf) do {                                                     \
        __builtin_amdgcn_sched_barrier(0);                                    \
        if ((t) < NSTEP - 1) asm volatile("s_waitcnt vmcnt(4)" ::: "memory"); \
        else                 asm volatile("s_waitcnt vmcnt(0)" ::: "memory"); \
        __builtin_amdgcn_s_barrier();                                         \
        __builtin_amdgcn_sched_barrier(0);                                    \
        if ((t) + 2 < NSTEP) STAGE(((t) + 2) % 3, (t) + 2);                   \
        const unsigned short* as_ = As + (buf) * 4096;                        \
        const unsigned short* bs_ = Bs + (buf) * 4096;                        \
        bf16x8 a00 = *(const bf16x8*)(as_ + oA00);                            \
        bf16x8 a01 = *(const bf16x8*)(as_ + oA01);                            \
        bf16x8 a10 = *(const bf16x8*)(as_ + oA10);                            \
        bf16x8 a11 = *(const bf16x8*)(as_ + oA11);                            \
        bf16x8 b00 = *(const bf16x8*)(bs_ + oB00);                            \
        bf16x8 b01 = *(const bf16x8*)(bs_ + oB01);                            \
        bf16x8 b10 = *(const bf16x8*)(bs_ + oB10);                            \
        bf16x8 b11 = *(const bf16x8*)(bs_ + oB11);                            \
        __builtin_amdgcn_s_setprio(1);                                        \
        acc[0][0] = __builtin_amdgcn_mfma_f32_16x16x32_bf16(a00, b00, acc[0][0], 0, 0, 0); \
        acc[0][0] = __builtin_amdgcn_mfma_f32_16x16x32_bf16(a01, b01, acc[0][0], 0, 0, 0); \
        acc[0][1] = __builtin_amdgcn_mfma_f32_16x16x32_bf16(a00, b10, acc[0][1], 0, 0, 0); \
        acc[0][1] = __builtin_amdgcn_mfma_f32_16x16x32_bf16(a01, b11, acc[0][1], 0, 0, 0); \
        acc[1][0] = __builtin_amdgcn_mfma_f32_16x16x32_bf16(a10, b00, acc[1][0], 0, 0, 0); \
        acc[1][0] = __builtin_amdgcn_mfma_f32_16x16x32_bf16(a11, b01, acc[1][0], 0, 0, 0); \
        acc[1][1] = __builtin_amdgcn_mfma_f32_16x16x32_bf16(a10, b10, acc[1][1], 0, 0, 0); \
        acc[1][1] = __builtin_amdgcn_mfma_f32_16x16x32_bf16(a11, b11, acc[1][1], 0, 0, 0); \
        __builtin_amdgcn_s_setprio(0);                                        \
    } while (0)

    #pragma unroll
    for (int t = 0; t < NSTEP; ++t) {
        BODY(t, t % 3);                     // fully unrolled: compile-time t
    }
#undef BODY
#undef STAGE

    // epilogue: C/D layout col=lane&15, row=(lane>>4)*4+reg (m89-verified);
    // rows [wr*32,+32) belong to batch 2bm+wr -> add c2s[wr][local col]
    #pragma unroll
    for (int m = 0; m < 2; ++m) {
        float vsum[4] = {0.f, 0.f, 0.f, 0.f};
        #pragma unroll
        for (int n = 0; n < 2; ++n) {
            const int lc  = wc * 32 + n * 16 + fr;
            const int col = bcol + lc;
            const float wo_ = Wo[col];
            const float ad_ = bp[col] + c2s[wr][lc];
            #pragma unroll
            for (int r = 0; r < 4; ++r) {
                float x = acc[m][n][r] + ad_;
                float th = 1.f - 2.f / (__expf(2.f * x) + 1.f);  // tanh(x)
                vsum[r] += th * wo_;
            }
        }
        #pragma unroll
        for (int r = 0; r < 4; ++r) {
            float v = vsum[r];
            v += __shfl_xor(v, 1, 16);
            v += __shfl_xor(v, 2, 16);
            v += __shfl_xor(v, 4, 16);
            v += __shfl_xor(v, 8, 16);
            if (fr == 0)
                atomicAdd(&out[brow + wr * 32 + m * 16 + fq * 4 + r], v);
        }
    }
}

// ---------------------------------------------------------------------------
extern "C" void kernel_launch(void* const* d_in, const int* in_sizes, int n_in,
                              void* d_out, int out_size, void* d_ws, size_t ws_size,
                              hipStream_t stream) {
    const float* seq   = (const float*)d_in[0];  // [B,S,H]
    // d_in[1] = context_h (unused by reference)
    const float* Wp    = (const float*)d_in[2];  // [D,D]
    const float* bp    = (const float*)d_in[3];  // [D]
    const float* Wo    = (const float*)d_in[4];  // [D]
    const float* bo    = (const float*)d_in[5];  // scalar
    const int*   pos   = (const int*)d_in[6];    // [B,L+1]
    // d_in[7] = doc_lens (unused by reference)
    float* out = (float*)d_out;                  // [B,L] = 2048

    unsigned short* Abf = (unsigned short*)d_ws;        // [MM][768]  3.1 MB
    unsigned short* Wbf = Abf + (size_t)MM * KA;        // [DD][DD]   4.7 MB
    unsigned short* Cls = Wbf + (size_t)DD * DD;        // [64][768]  98 KB

    const int ninit = (MM + 191) / 192;                 // 11
    prep<<<MM + 3072 + 64 + ninit, 192, 0, stream>>>(seq, pos, Wp, bo,
                                                     Abf, Wbf, Cls, out);
    gemm_mfma<<<768, 256, 0, stream>>>(Abf, Wbf, Cls, bp, Wo, out);
}

// Round 12
// 38.156 us; speedup vs baseline: 1.4398x; 1.4398x over previous
//
#include <hip/hip_runtime.h>
#include <hip/hip_bf16.h>

// Problem constants (fixed by reference):
#define SS 512
#define HH 768
#define LL 32
#define DD 1536   // 2*H
#define MM 2048   // B*L rows
#define KA 768    // main-GEMM K (mean half; CLS half collapses 32x into C2)
#define NSTEP 12  // K-steps of 64

typedef float f32x4 __attribute__((ext_vector_type(4)));
typedef short bf16x8 __attribute__((ext_vector_type(8)));

__device__ __forceinline__ unsigned short f2bf(float x) {
    union { float f; unsigned u; } v; v.f = x;
    unsigned r = v.u + 0x7fff + ((v.u >> 16) & 1);   // round-to-nearest-even
    return (unsigned short)(r >> 16);
}

__device__ __forceinline__ void gload16(const unsigned short* g, unsigned short* l) {
    // async global->LDS, 16B/lane; LDS dest = wave-uniform base + lane*16
    __builtin_amdgcn_global_load_lds(
        (const __attribute__((address_space(1))) void*)g,
        (__attribute__((address_space(3))) void*)l, 16, 0, 0);
}

// ---------------------------------------------------------------------------
// Fused prep (256 thr/block), grid 3616:
//   [0,24)           : C2 MFMA blocks — C2[0:64][blk*64 ..+64) =
//                      cls(bf16) @ Wp[col][768:1536)(bf16)^T, K=768.
//                      Reads ONLY raw f32 inputs -> no race with other blocks.
//                      Coalesced float4 loads, in-reg f2bf, swizzled ds_write,
//                      R7-verified fragment geometry, single LDS buffer.
//   [24,2072)        : mean rows -> Abf[row][768] bf16 (scalar f32, 3/thread)
//   [2072,3608)      : W_pool mean-half row copy f32->bf16 (row n, k<768)
//   [3608,3616)      : init logits to b_out
// ---------------------------------------------------------------------------
__global__ __launch_bounds__(256)
void prep(const float* __restrict__ seq, const int* __restrict__ pos,
          const float* __restrict__ Wp, const float* __restrict__ bo,
          unsigned short* __restrict__ Abf, unsigned short* __restrict__ Wbf,
          float* __restrict__ C2, float* __restrict__ out) {
    __shared__ unsigned short CAs[64 * 64];   // 8 KB (C2 blocks only)
    __shared__ unsigned short CBs[64 * 64];   // 8 KB
    const int blk = blockIdx.x;
    const int tid = threadIdx.x;              // 0..255

    if (blk < 24) {
        // ---- C2 MFMA block: cols [bcol, bcol+64) ----
        const int bcol = blk * 64;
        const int lane = tid & 63;
        const int wid  = tid >> 6;
        const int fr = lane & 15, fq = lane >> 4;
        const int wr = wid >> 1,  wc = wid & 1;
        // staging: thread -> A/W row crow, float4 group cf
        const int crow = tid >> 2;            // 0..63
        const int cf   = tid & 3;
        const float* gA = seq + (size_t)crow * SS * HH;            // cls row b
        const float* gW = Wp  + (size_t)(bcol + crow) * DD + HH;   // CLS half
        // fragment read offsets (R7-verified): slot = chunk ^ (row&7)
        const int s0 = fq ^ (fr & 7);
        const int s1 = s0 ^ 4;
        const int rA = wr * 32 + fr;
        const int rB = wc * 32 + fr;
        const int oA00 = rA * 64 + s0 * 8, oA01 = rA * 64 + s1 * 8;
        const int oA10 = oA00 + 16 * 64,   oA11 = oA01 + 16 * 64;
        const int oB00 = rB * 64 + s0 * 8, oB01 = rB * 64 + s1 * 8;
        const int oB10 = oB00 + 16 * 64,   oB11 = oB01 + 16 * 64;

        f32x4 acc[2][2] = {};
        for (int t = 0; t < NSTEP; ++t) {
            const int k0 = t * 64;
            __syncthreads();                  // prev iter's reads done
            #pragma unroll
            for (int j = 0; j < 4; ++j) {
                const int f4   = cf + j * 4;              // 0..15
                const int slot = (f4 >> 1) ^ (crow & 7);
                const int off  = crow * 64 + slot * 8 + (f4 & 1) * 4;
                float4 av = *(const float4*)(gA + k0 + f4 * 4);
                float4 wv = *(const float4*)(gW + k0 + f4 * 4);
                ushort4 au, wu;
                au.x = f2bf(av.x); au.y = f2bf(av.y);
                au.z = f2bf(av.z); au.w = f2bf(av.w);
                wu.x = f2bf(wv.x); wu.y = f2bf(wv.y);
                wu.z = f2bf(wv.z); wu.w = f2bf(wv.w);
                *(ushort4*)&CAs[off] = au;
                *(ushort4*)&CBs[off] = wu;
            }
            __syncthreads();                  // tile staged
            bf16x8 a00 = *(const bf16x8*)&CAs[oA00];
            bf16x8 a01 = *(const bf16x8*)&CAs[oA01];
            bf16x8 a10 = *(const bf16x8*)&CAs[oA10];
            bf16x8 a11 = *(const bf16x8*)&CAs[oA11];
            bf16x8 b00 = *(const bf16x8*)&CBs[oB00];
            bf16x8 b01 = *(const bf16x8*)&CBs[oB01];
            bf16x8 b10 = *(const bf16x8*)&CBs[oB10];
            bf16x8 b11 = *(const bf16x8*)&CBs[oB11];
            acc[0][0] = __builtin_amdgcn_mfma_f32_16x16x32_bf16(a00, b00, acc[0][0], 0, 0, 0);
            acc[0][0] = __builtin_amdgcn_mfma_f32_16x16x32_bf16(a01, b01, acc[0][0], 0, 0, 0);
            acc[0][1] = __builtin_amdgcn_mfma_f32_16x16x32_bf16(a00, b10, acc[0][1], 0, 0, 0);
            acc[0][1] = __builtin_amdgcn_mfma_f32_16x16x32_bf16(a01, b11, acc[0][1], 0, 0, 0);
            acc[1][0] = __builtin_amdgcn_mfma_f32_16x16x32_bf16(a10, b00, acc[1][0], 0, 0, 0);
            acc[1][0] = __builtin_amdgcn_mfma_f32_16x16x32_bf16(a11, b01, acc[1][0], 0, 0, 0);
            acc[1][1] = __builtin_amdgcn_mfma_f32_16x16x32_bf16(a10, b10, acc[1][1], 0, 0, 0);
            acc[1][1] = __builtin_amdgcn_mfma_f32_16x16x32_bf16(a11, b11, acc[1][1], 0, 0, 0);
        }
        // write C2: D-row = batch, col = bcol + ... (m89 layout)
        #pragma unroll
        for (int m = 0; m < 2; ++m)
            #pragma unroll
            for (int n = 0; n < 2; ++n) {
                const int col = bcol + wc * 32 + n * 16 + fr;
                #pragma unroll
                for (int r = 0; r < 4; ++r) {
                    const int row = wr * 32 + m * 16 + fq * 4 + r;
                    C2[(size_t)row * DD + col] = acc[m][n][r];
                }
            }
    } else if (blk < 24 + MM) {
        // ---- mean row ----
        const int row = blk - 24;
        const int b = row >> 5;
        const int l = row & 31;
        const int* pb = pos + b * (LL + 1);
        int start = pb[l] + 1;
        int end   = pb[l + 1] + 1;
        if (l == LL - 1) end += 1;            // last clause also takes the SEP
        float inv = 1.0f / (float)(end - start);
        const float* base = seq + (size_t)b * SS * HH;
        float a0 = 0.f, a1 = 0.f, a2 = 0.f;
        for (int t = start; t < end; ++t) {
            const float* p = base + (size_t)t * HH;
            a0 += p[tid]; a1 += p[tid + 256]; a2 += p[tid + 512];
        }
        unsigned short* o = Abf + (size_t)row * KA;
        o[tid]       = f2bf(a0 * inv);
        o[tid + 256] = f2bf(a1 * inv);
        o[tid + 512] = f2bf(a2 * inv);
    } else if (blk < 24 + MM + DD) {
        // ---- W_pool mean-half row copy ----
        const int n = blk - 24 - MM;
        const float* src = Wp + (size_t)n * DD;
        unsigned short* dst = Wbf + (size_t)n * KA;
        dst[tid]       = f2bf(src[tid]);
        dst[tid + 256] = f2bf(src[tid + 256]);
        dst[tid + 512] = f2bf(src[tid + 512]);
    } else {
        const int i = (blk - 24 - MM - DD) * 256 + tid;
        if (i < MM) out[i] = bo[0];
    }
}

// ---------------------------------------------------------------------------
// Main GEMM over the MEAN half only (K=768, 12 steps) — exact R7 structure:
// 64x64 tile, 4 waves (2x2 of 32x32), 3 LDS bufs, stage-ahead-2, counted
// vmcnt(4), one barrier/step, verified XOR swizzle, XCD chunking.
// Epilogue: tanh(acc + C2[batch][col] + b_pool) * W_out, shfl reduce, atomic.
// ---------------------------------------------------------------------------
__global__ __launch_bounds__(256, 3)
void gemm_mfma(const unsigned short* __restrict__ A,   // [MM][768] bf16 means
               const unsigned short* __restrict__ Bm,  // [DD][768] bf16 W mean-half
               const float* __restrict__ C2g,          // [64][DD] f32
               const float* __restrict__ bp,           // [DD]
               const float* __restrict__ Wo,           // [DD]
               float* __restrict__ out) {              // [MM]
    __shared__ unsigned short As[3 * 4096];  // 3 bufs x 64x64 bf16 = 24 KB
    __shared__ unsigned short Bs[3 * 4096];  // 24 KB (48 KB total -> 3 blk/CU)
    const int tid  = threadIdx.x;
    const int wid  = tid >> 6;
    const int lane = tid & 63;
    const int fr   = lane & 15;
    const int fq   = lane >> 4;
    const int wr   = wid >> 1, wc = wid & 1;

    // XCD-aware chunking: xcd = blk&7 (HW round-robin); chunk 8 bm x 12 bn
    const int blk = blockIdx.x;             // 0..767
    const int c = blk & 7;
    const int i = blk >> 3;                 // 0..95
    const int bm = ((c >> 1) << 3) + (i & 7);     // 0..31
    const int bn = (c & 1) * 12 + (i >> 3);       // 0..23
    const int brow = bm * 64;
    const int bcol = bn * 64;

    // staging: thread t -> row t>>3 (and +32), 16B chunk (t&7)^(row&7)
    // (source pre-swizzle; LDS dest stays linear per rule #21)
    const int srow = tid >> 3;              // 0..31 ; +32 for second half
    const int sc   = (tid & 7) ^ (srow & 7);      // (srow+32)&7 == srow&7
    const unsigned short* gA = A  + (size_t)(brow + srow) * KA + sc * 8;
    const unsigned short* gB = Bm + (size_t)(bcol + srow) * KA + sc * 8;
    unsigned short* asW = As + wid * 512;   // wave-uniform LDS dest base
    unsigned short* bsW = Bs + wid * 512;

#define STAGE(buf, kt) do {                                          \
        gload16(gA + (kt) * 64,           asW + (buf) * 4096);       \
        gload16(gA + (kt) * 64 + 32 * KA, asW + (buf) * 4096 + 2048);\
        gload16(gB + (kt) * 64,           bsW + (buf) * 4096);       \
        gload16(gB + (kt) * 64 + 32 * KA, bsW + (buf) * 4096 + 2048);\
    } while (0)

    // swizzled fragment-read offsets: slot = desired_chunk ^ (row&7)
    const int s0 = fq ^ (fr & 7);
    const int s1 = s0 ^ 4;
    const int rA = wr * 32 + fr;            // m adds 16
    const int rB = wc * 32 + fr;            // n adds 16
    const int oA00 = rA * 64 + s0 * 8, oA01 = rA * 64 + s1 * 8;
    const int oA10 = oA00 + 16 * 64,   oA11 = oA01 + 16 * 64;
    const int oB00 = rB * 64 + s0 * 8, oB01 = rB * 64 + s1 * 8;
    const int oB10 = oB00 + 16 * 64,   oB11 = oB01 + 16 * 64;

    f32x4 acc[2][2] = {};

    STAGE(0, 0); STAGE(1, 1);               // depth-2 prologue (8 loads/wave)

#define BODY(t, buf) do {                                                     \
        __builtin_amdgcn_sched_barrier(0);                                    \
        if ((t) < NSTEP - 1) asm volatile("s_waitcnt vmcnt(4)" ::: "memory"); \
        else                 asm volatile("s_waitcnt vmcnt(0)" ::: "memory"); \
        __builtin_amdgcn_s_barrier();                                         \
        __builtin_amdgcn_sched_barrier(0);                                    \
        if ((t) + 2 < NSTEP) STAGE(((t) + 2) % 3, (t) + 2);                   \
        const unsigned short* as_ = As + (buf) * 4096;                        \
        const unsigned short* bs_ = Bs + (buf) * 4096;                        \
        bf16x8 a00 = *(const bf16x8*)(as_ + oA00);                            \
        bf16x8 a01 = *(const bf16x8*)(as_ + oA01);                            \
        bf16x8 a10 = *(const bf16x8*)(as_ + oA10);                            \
        bf16x8 a11 = *(const bf16x8*)(as_ + oA11);                            \
        bf16x8 b00 = *(const bf16x8*)(bs_ + oB00);                            \
        bf16x8 b01 = *(const bf16x8*)(bs_ + oB01);                            \
        bf16x8 b10 = *(const bf16x8*)(bs_ + oB10);                            \
        bf16x8 b11 = *(const bf16x8*)(bs_ + oB11);                            \
        __builtin_amdgcn_s_setprio(1);                                        \
        acc[0][0] = __builtin_amdgcn_mfma_f32_16x16x32_bf16(a00, b00, acc[0][0], 0, 0, 0); \
        acc[0][0] = __builtin_amdgcn_mfma_f32_16x16x32_bf16(a01, b01, acc[0][0], 0, 0, 0); \
        acc[0][1] = __builtin_amdgcn_mfma_f32_16x16x32_bf16(a00, b10, acc[0][1], 0, 0, 0); \
        acc[0][1] = __builtin_amdgcn_mfma_f32_16x16x32_bf16(a01, b11, acc[0][1], 0, 0, 0); \
        acc[1][0] = __builtin_amdgcn_mfma_f32_16x16x32_bf16(a10, b00, acc[1][0], 0, 0, 0); \
        acc[1][0] = __builtin_amdgcn_mfma_f32_16x16x32_bf16(a11, b01, acc[1][0], 0, 0, 0); \
        acc[1][1] = __builtin_amdgcn_mfma_f32_16x16x32_bf16(a10, b10, acc[1][1], 0, 0, 0); \
        acc[1][1] = __builtin_amdgcn_mfma_f32_16x16x32_bf16(a11, b11, acc[1][1], 0, 0, 0); \
        __builtin_amdgcn_s_setprio(0);                                        \
    } while (0)

    #pragma unroll
    for (int t = 0; t < NSTEP; ++t) {
        BODY(t, t % 3);                     // fully unrolled: compile-time t
    }
#undef BODY
#undef STAGE

    // epilogue: C/D layout col=lane&15, row=(lane>>4)*4+reg (m89-verified);
    // rows [wr*32,+32) are batch 2bm+wr -> add C2[2bm+wr][col] before tanh
    const float* c2row = C2g + (size_t)(2 * bm + wr) * DD;
    float wo_[2], ad_[2];
    #pragma unroll
    for (int n = 0; n < 2; ++n) {
        const int col = bcol + wc * 32 + n * 16 + fr;
        wo_[n] = Wo[col];
        ad_[n] = bp[col] + c2row[col];
    }
    #pragma unroll
    for (int m = 0; m < 2; ++m) {
        float vsum[4] = {0.f, 0.f, 0.f, 0.f};
        #pragma unroll
        for (int n = 0; n < 2; ++n) {
            #pragma unroll
            for (int r = 0; r < 4; ++r) {
                float x = acc[m][n][r] + ad_[n];
                float th = 1.f - 2.f / (__expf(2.f * x) + 1.f);  // tanh(x)
                vsum[r] += th * wo_[n];
            }
        }
        #pragma unroll
        for (int r = 0; r < 4; ++r) {
            float v = vsum[r];
            v += __shfl_xor(v, 1, 16);
            v += __shfl_xor(v, 2, 16);
            v += __shfl_xor(v, 4, 16);
            v += __shfl_xor(v, 8, 16);
            if (fr == 0)
                atomicAdd(&out[brow + wr * 32 + m * 16 + fq * 4 + r], v);
        }
    }
}

// ---------------------------------------------------------------------------
extern "C" void kernel_launch(void* const* d_in, const int* in_sizes, int n_in,
                              void* d_out, int out_size, void* d_ws, size_t ws_size,
                              hipStream_t stream) {
    const float* seq   = (const float*)d_in[0];  // [B,S,H]
    // d_in[1] = context_h (unused by reference)
    const float* Wp    = (const float*)d_in[2];  // [D,D]
    const float* bp    = (const float*)d_in[3];  // [D]
    const float* Wo    = (const float*)d_in[4];  // [D]
    const float* bo    = (const float*)d_in[5];  // scalar
    const int*   pos   = (const int*)d_in[6];    // [B,L+1]
    // d_in[7] = doc_lens (unused by reference)
    float* out = (float*)d_out;                  // [B,L] = 2048

    unsigned short* Abf = (unsigned short*)d_ws;        // [2048][768] 3.15 MB
    unsigned short* Wbf = Abf + (size_t)MM * KA;        // [1536][768] 2.36 MB
    float*          C2  = (float*)(Wbf + (size_t)DD * KA);  // [64][1536] 0.39 MB

    const int grid = 24 + MM + DD + (MM + 255) / 256;   // 3616
    prep<<<grid, 256, 0, stream>>>(seq, pos, Wp, bo, Abf, Wbf, C2, out);
    gemm_mfma<<<768, 256, 0, stream>>>(Abf, Wbf, C2, bp, Wo, out);
}

// Round 13
// 36.305 us; speedup vs baseline: 1.5132x; 1.0510x over previous
//
#include <hip/hip_runtime.h>
#include <hip/hip_bf16.h>

// Problem constants (fixed by reference):
#define SS 512
#define HH 768
#define LL 32
#define DD 1536   // 2*H
#define MM 2048   // B*L rows
#define KA 768    // main-GEMM K (mean half; CLS half collapses 32x into C2)
#define NSTEP 12  // K-steps of 64

typedef float f32x4 __attribute__((ext_vector_type(4)));
typedef short bf16x8 __attribute__((ext_vector_type(8)));

__device__ __forceinline__ unsigned short f2bf(float x) {
    union { float f; unsigned u; } v; v.f = x;
    unsigned r = v.u + 0x7fff + ((v.u >> 16) & 1);   // round-to-nearest-even
    return (unsigned short)(r >> 16);
}

__device__ __forceinline__ void gload16(const unsigned short* g, unsigned short* l) {
    // async global->LDS, 16B/lane; LDS dest = wave-uniform base + lane*16
    __builtin_amdgcn_global_load_lds(
        (const __attribute__((address_space(1))) void*)g,
        (__attribute__((address_space(3))) void*)l, 16, 0, 0);
}

// ---------------------------------------------------------------------------
// Fused prep (256 thr/block), grid 3616:
//   [0,24)       : C2 MFMA blocks — C2[0:64][blk*64..+64) = cls(bf16) @
//                  Wp[col][768:1536)(bf16)^T, K=768. (unchanged from R12)
//   [24,2072)    : mean rows -> Abf[row][768] bf16 — float4 loads (16B/lane,
//                  threads 0..191 active; HBM-bound so idle lanes are free)
//   [2072,3608)  : W_pool mean-half row copy f32->bf16 — float4 loads
//   [3608,3616)  : init logits to b_out
// ---------------------------------------------------------------------------
__global__ __launch_bounds__(256)
void prep(const float* __restrict__ seq, const int* __restrict__ pos,
          const float* __restrict__ Wp, const float* __restrict__ bo,
          unsigned short* __restrict__ Abf, unsigned short* __restrict__ Wbf,
          float* __restrict__ C2, float* __restrict__ out) {
    __shared__ unsigned short CAs[64 * 64];   // 8 KB (C2 blocks only)
    __shared__ unsigned short CBs[64 * 64];   // 8 KB
    const int blk = blockIdx.x;
    const int tid = threadIdx.x;              // 0..255

    if (blk < 24) {
        // ---- C2 MFMA block: cols [bcol, bcol+64) ----
        const int bcol = blk * 64;
        const int lane = tid & 63;
        const int wid  = tid >> 6;
        const int fr = lane & 15, fq = lane >> 4;
        const int wr = wid >> 1,  wc = wid & 1;
        const int crow = tid >> 2;            // 0..63
        const int cf   = tid & 3;
        const float* gA = seq + (size_t)crow * SS * HH;            // cls row b
        const float* gW = Wp  + (size_t)(bcol + crow) * DD + HH;   // CLS half
        const int s0 = fq ^ (fr & 7);
        const int s1 = s0 ^ 4;
        const int rA = wr * 32 + fr;
        const int rB = wc * 32 + fr;
        const int oA00 = rA * 64 + s0 * 8, oA01 = rA * 64 + s1 * 8;
        const int oA10 = oA00 + 16 * 64,   oA11 = oA01 + 16 * 64;
        const int oB00 = rB * 64 + s0 * 8, oB01 = rB * 64 + s1 * 8;
        const int oB10 = oB00 + 16 * 64,   oB11 = oB01 + 16 * 64;

        f32x4 acc[2][2] = {};
        for (int t = 0; t < NSTEP; ++t) {
            const int k0 = t * 64;
            __syncthreads();                  // prev iter's reads done
            #pragma unroll
            for (int j = 0; j < 4; ++j) {
                const int f4   = cf + j * 4;              // 0..15
                const int slot = (f4 >> 1) ^ (crow & 7);
                const int off  = crow * 64 + slot * 8 + (f4 & 1) * 4;
                float4 av = *(const float4*)(gA + k0 + f4 * 4);
                float4 wv = *(const float4*)(gW + k0 + f4 * 4);
                ushort4 au, wu;
                au.x = f2bf(av.x); au.y = f2bf(av.y);
                au.z = f2bf(av.z); au.w = f2bf(av.w);
                wu.x = f2bf(wv.x); wu.y = f2bf(wv.y);
                wu.z = f2bf(wv.z); wu.w = f2bf(wv.w);
                *(ushort4*)&CAs[off] = au;
                *(ushort4*)&CBs[off] = wu;
            }
            __syncthreads();                  // tile staged
            bf16x8 a00 = *(const bf16x8*)&CAs[oA00];
            bf16x8 a01 = *(const bf16x8*)&CAs[oA01];
            bf16x8 a10 = *(const bf16x8*)&CAs[oA10];
            bf16x8 a11 = *(const bf16x8*)&CAs[oA11];
            bf16x8 b00 = *(const bf16x8*)&CBs[oB00];
            bf16x8 b01 = *(const bf16x8*)&CBs[oB01];
            bf16x8 b10 = *(const bf16x8*)&CBs[oB10];
            bf16x8 b11 = *(const bf16x8*)&CBs[oB11];
            acc[0][0] = __builtin_amdgcn_mfma_f32_16x16x32_bf16(a00, b00, acc[0][0], 0, 0, 0);
            acc[0][0] = __builtin_amdgcn_mfma_f32_16x16x32_bf16(a01, b01, acc[0][0], 0, 0, 0);
            acc[0][1] = __builtin_amdgcn_mfma_f32_16x16x32_bf16(a00, b10, acc[0][1], 0, 0, 0);
            acc[0][1] = __builtin_amdgcn_mfma_f32_16x16x32_bf16(a01, b11, acc[0][1], 0, 0, 0);
            acc[1][0] = __builtin_amdgcn_mfma_f32_16x16x32_bf16(a10, b00, acc[1][0], 0, 0, 0);
            acc[1][0] = __builtin_amdgcn_mfma_f32_16x16x32_bf16(a11, b01, acc[1][0], 0, 0, 0);
            acc[1][1] = __builtin_amdgcn_mfma_f32_16x16x32_bf16(a10, b10, acc[1][1], 0, 0, 0);
            acc[1][1] = __builtin_amdgcn_mfma_f32_16x16x32_bf16(a11, b11, acc[1][1], 0, 0, 0);
        }
        #pragma unroll
        for (int m = 0; m < 2; ++m)
            #pragma unroll
            for (int n = 0; n < 2; ++n) {
                const int col = bcol + wc * 32 + n * 16 + fr;
                #pragma unroll
                for (int r = 0; r < 4; ++r) {
                    const int row = wr * 32 + m * 16 + fq * 4 + r;
                    C2[(size_t)row * DD + col] = acc[m][n][r];
                }
            }
    } else if (blk < 24 + MM) {
        // ---- mean row: float4 per thread (threads 0..191 active) ----
        const int row = blk - 24;
        if (tid < 192) {
            const int b = row >> 5;
            const int l = row & 31;
            const int* pb = pos + b * (LL + 1);
            int start = pb[l] + 1;
            int end   = pb[l + 1] + 1;
            if (l == LL - 1) end += 1;        // last clause also takes the SEP
            float inv = 1.0f / (float)(end - start);
            const float* base = seq + (size_t)b * SS * HH;
            float4 a = make_float4(0.f, 0.f, 0.f, 0.f);
            for (int t = start; t < end; ++t) {
                float4 v = reinterpret_cast<const float4*>(base + (size_t)t * HH)[tid];
                a.x += v.x; a.y += v.y; a.z += v.z; a.w += v.w;
            }
            ushort4 m;
            m.x = f2bf(a.x * inv); m.y = f2bf(a.y * inv);
            m.z = f2bf(a.z * inv); m.w = f2bf(a.w * inv);
            reinterpret_cast<ushort4*>(Abf + (size_t)row * KA)[tid] = m;
        }
    } else if (blk < 24 + MM + DD) {
        // ---- W_pool mean-half row copy: float4 (threads 0..191) ----
        const int n = blk - 24 - MM;
        if (tid < 192) {
            float4 v = reinterpret_cast<const float4*>(Wp + (size_t)n * DD)[tid];
            ushort4 o;
            o.x = f2bf(v.x); o.y = f2bf(v.y); o.z = f2bf(v.z); o.w = f2bf(v.w);
            reinterpret_cast<ushort4*>(Wbf + (size_t)n * KA)[tid] = o;
        }
    } else {
        const int i = (blk - 24 - MM - DD) * 256 + tid;
        if (i < MM) out[i] = bo[0];
    }
}

// ---------------------------------------------------------------------------
// Main GEMM over the MEAN half only (K=768, 12 steps) — exact R12 structure:
// 64x64 tile, 4 waves (2x2 of 32x32), 3 LDS bufs, stage-ahead-2, counted
// vmcnt(4), one barrier/step, verified XOR swizzle, XCD chunking.
// Epilogue: tanh(acc + C2[batch][col] + b_pool) * W_out, shfl reduce, atomic.
// ---------------------------------------------------------------------------
__global__ __launch_bounds__(256, 3)
void gemm_mfma(const unsigned short* __restrict__ A,   // [MM][768] bf16 means
               const unsigned short* __restrict__ Bm,  // [DD][768] bf16 W mean-half
               const float* __restrict__ C2g,          // [64][DD] f32
               const float* __restrict__ bp,           // [DD]
               const float* __restrict__ Wo,           // [DD]
               float* __restrict__ out) {              // [MM]
    __shared__ unsigned short As[3 * 4096];  // 3 bufs x 64x64 bf16 = 24 KB
    __shared__ unsigned short Bs[3 * 4096];  // 24 KB (48 KB total -> 3 blk/CU)
    const int tid  = threadIdx.x;
    const int wid  = tid >> 6;
    const int lane = tid & 63;
    const int fr   = lane & 15;
    const int fq   = lane >> 4;
    const int wr   = wid >> 1, wc = wid & 1;

    // XCD-aware chunking: xcd = blk&7 (HW round-robin); chunk 8 bm x 12 bn
    const int blk = blockIdx.x;             // 0..767
    const int c = blk & 7;
    const int i = blk >> 3;                 // 0..95
    const int bm = ((c >> 1) << 3) + (i & 7);     // 0..31
    const int bn = (c & 1) * 12 + (i >> 3);       // 0..23
    const int brow = bm * 64;
    const int bcol = bn * 64;

    // staging: thread t -> row t>>3 (and +32), 16B chunk (t&7)^(row&7)
    // (source pre-swizzle; LDS dest stays linear per rule #21)
    const int srow = tid >> 3;              // 0..31 ; +32 for second half
    const int sc   = (tid & 7) ^ (srow & 7);      // (srow+32)&7 == srow&7
    const unsigned short* gA = A  + (size_t)(brow + srow) * KA + sc * 8;
    const unsigned short* gB = Bm + (size_t)(bcol + srow) * KA + sc * 8;
    unsigned short* asW = As + wid * 512;   // wave-uniform LDS dest base
    unsigned short* bsW = Bs + wid * 512;

#define STAGE(buf, kt) do {                                          \
        gload16(gA + (kt) * 64,           asW + (buf) * 4096);       \
        gload16(gA + (kt) * 64 + 32 * KA, asW + (buf) * 4096 + 2048);\
        gload16(gB + (kt) * 64,           bsW + (buf) * 4096);       \
        gload16(gB + (kt) * 64 + 32 * KA, bsW + (buf) * 4096 + 2048);\
    } while (0)

    // swizzled fragment-read offsets: slot = desired_chunk ^ (row&7)
    const int s0 = fq ^ (fr & 7);
    const int s1 = s0 ^ 4;
    const int rA = wr * 32 + fr;            // m adds 16
    const int rB = wc * 32 + fr;            // n adds 16
    const int oA00 = rA * 64 + s0 * 8, oA01 = rA * 64 + s1 * 8;
    const int oA10 = oA00 + 16 * 64,   oA11 = oA01 + 16 * 64;
    const int oB00 = rB * 64 + s0 * 8, oB01 = rB * 64 + s1 * 8;
    const int oB10 = oB00 + 16 * 64,   oB11 = oB01 + 16 * 64;

    f32x4 acc[2][2] = {};

    STAGE(0, 0); STAGE(1, 1);               // depth-2 prologue (8 loads/wave)

#define BODY(t, buf) do {                                                     \
        __builtin_amdgcn_sched_barrier(0);                                    \
        if ((t) < NSTEP - 1) asm volatile("s_waitcnt vmcnt(4)" ::: "memory"); \
        else                 asm volatile("s_waitcnt vmcnt(0)" ::: "memory"); \
        __builtin_amdgcn_s_barrier();                                         \
        __builtin_amdgcn_sched_barrier(0);                                    \
        if ((t) + 2 < NSTEP) STAGE(((t) + 2) % 3, (t) + 2);                   \
        const unsigned short* as_ = As + (buf) * 4096;                        \
        const unsigned short* bs_ = Bs + (buf) * 4096;                        \
        bf16x8 a00 = *(const bf16x8*)(as_ + oA00);                            \
        bf16x8 a01 = *(const bf16x8*)(as_ + oA01);                            \
        bf16x8 a10 = *(const bf16x8*)(as_ + oA10);                            \
        bf16x8 a11 = *(const bf16x8*)(as_ + oA11);                            \
        bf16x8 b00 = *(const bf16x8*)(bs_ + oB00);                            \
        bf16x8 b01 = *(const bf16x8*)(bs_ + oB01);                            \
        bf16x8 b10 = *(const bf16x8*)(bs_ + oB10);                            \
        bf16x8 b11 = *(const bf16x8*)(bs_ + oB11);                            \
        __builtin_amdgcn_s_setprio(1);                                        \
        acc[0][0] = __builtin_amdgcn_mfma_f32_16x16x32_bf16(a00, b00, acc[0][0], 0, 0, 0); \
        acc[0][0] = __builtin_amdgcn_mfma_f32_16x16x32_bf16(a01, b01, acc[0][0], 0, 0, 0); \
        acc[0][1] = __builtin_amdgcn_mfma_f32_16x16x32_bf16(a00, b10, acc[0][1], 0, 0, 0); \
        acc[0][1] = __builtin_amdgcn_mfma_f32_16x16x32_bf16(a01, b11, acc[0][1], 0, 0, 0); \
        acc[1][0] = __builtin_amdgcn_mfma_f32_16x16x32_bf16(a10, b00, acc[1][0], 0, 0, 0); \
        acc[1][0] = __builtin_amdgcn_mfma_f32_16x16x32_bf16(a11, b01, acc[1][0], 0, 0, 0); \
        acc[1][1] = __builtin_amdgcn_mfma_f32_16x16x32_bf16(a10, b10, acc[1][1], 0, 0, 0); \
        acc[1][1] = __builtin_amdgcn_mfma_f32_16x16x32_bf16(a11, b11, acc[1][1], 0, 0, 0); \
        __builtin_amdgcn_s_setprio(0);                                        \
    } while (0)

    #pragma unroll
    for (int t = 0; t < NSTEP; ++t) {
        BODY(t, t % 3);                     // fully unrolled: compile-time t
    }
#undef BODY
#undef STAGE

    // epilogue: C/D layout col=lane&15, row=(lane>>4)*4+reg (m89-verified);
    // rows [wr*32,+32) are batch 2bm+wr -> add C2[2bm+wr][col] before tanh
    const float* c2row = C2g + (size_t)(2 * bm + wr) * DD;
    float wo_[2], ad_[2];
    #pragma unroll
    for (int n = 0; n < 2; ++n) {
        const int col = bcol + wc * 32 + n * 16 + fr;
        wo_[n] = Wo[col];
        ad_[n] = bp[col] + c2row[col];
    }
    #pragma unroll
    for (int m = 0; m < 2; ++m) {
        float vsum[4] = {0.f, 0.f, 0.f, 0.f};
        #pragma unroll
        for (int n = 0; n < 2; ++n) {
            #pragma unroll
            for (int r = 0; r < 4; ++r) {
                float x = acc[m][n][r] + ad_[n];
                float th = 1.f - 2.f / (__expf(2.f * x) + 1.f);  // tanh(x)
                vsum[r] += th * wo_[n];
            }
        }
        #pragma unroll
        for (int r = 0; r < 4; ++r) {
            float v = vsum[r];
            v += __shfl_xor(v, 1, 16);
            v += __shfl_xor(v, 2, 16);
            v += __shfl_xor(v, 4, 16);
            v += __shfl_xor(v, 8, 16);
            if (fr == 0)
                atomicAdd(&out[brow + wr * 32 + m * 16 + fq * 4 + r], v);
        }
    }
}

// ---------------------------------------------------------------------------
extern "C" void kernel_launch(void* const* d_in, const int* in_sizes, int n_in,
                              void* d_out, int out_size, void* d_ws, size_t ws_size,
                              hipStream_t stream) {
    const float* seq   = (const float*)d_in[0];  // [B,S,H]
    // d_in[1] = context_h (unused by reference)
    const float* Wp    = (const float*)d_in[2];  // [D,D]
    const float* bp    = (const float*)d_in[3];  // [D]
    const float* Wo    = (const float*)d_in[4];  // [D]
    const float* bo    = (const float*)d_in[5];  // scalar
    const int*   pos   = (const int*)d_in[6];    // [B,L+1]
    // d_in[7] = doc_lens (unused by reference)
    float* out = (float*)d_out;                  // [B,L] = 2048

    unsigned short* Abf = (unsigned short*)d_ws;        // [2048][768] 3.15 MB
    unsigned short* Wbf = Abf + (size_t)MM * KA;        // [1536][768] 2.36 MB
    float*          C2  = (float*)(Wbf + (size_t)DD * KA);  // [64][1536] 0.39 MB

    const int grid = 24 + MM + DD + (MM + 255) / 256;   // 3616
    prep<<<grid, 256, 0, stream>>>(seq, pos, Wp, bo, Abf, Wbf, C2, out);
    gemm_mfma<<<768, 256, 0, stream>>>(Abf, Wbf, C2, bp, Wo, out);
}